// Round 8
// baseline (486.318 us; speedup 1.0000x reference)
//
#include <hip/hip_runtime.h>

// WarpAdjoint: bilinear forward-splat (scatter-add), summed over T.
// x_re, x_im: [B, T, M, N] f32;  u: [B, T, M, N, 2] f32 (u[...,0]=dx, u[...,1]=dy)
// out: real-part-only [B,M,N] f32 (harness), or interleaved complex64 if out_size says so.
//
// R6 post-mortem: single-kernel version was 288.8us with ALL pipes idle
// (HBM 4.4%, VALU 9.3%, LDS-conflict ~0) -> bottleneck by elimination is the
// ~5.3M device-scope global_atomic_add_f32 flush. This version removes ALL
// flush atomics: phase 1 stores each block's 48x48 halo tile to d_ws (plain,
// coalesced), phase 2 gathers <=4 covering tiles per output pixel.

#define BB   8
#define TT   12
#define MM   384
#define NN   384
#define TS   32                 // tile size
#define HALO 8                  // covers ~8 sigma of N(0,1) flow
#define LW   (TS + 2*HALO)      // 48
#define NTX  (NN/TS)            // 12
#define NTY  (MM/TS)            // 12
#define TILES (NTX*NTY)         // 144

// ---------------- Phase 1: splat into LDS tile, then store tile to ws -------
template<bool CPLX, bool USE_WS>
__global__ __launch_bounds__(256)
void splat_phase1(const float* __restrict__ xr, const float* __restrict__ xi,
                  const float* __restrict__ u, float* __restrict__ out,
                  float* __restrict__ ws)
{
    // complex: interleaved (re,im), row stride 98 words (98%32==2 -> ~2-way, free)
    // real:    row stride 49 words (odd -> conflict-free columns)
    constexpr int ROWW = CPLX ? (2 * LW + 2) : (LW + 1);
    constexpr int ELEMS = CPLX ? (LW * LW * 2) : (LW * LW);   // compact ws tile
    __shared__ float tile[LW * ROWW];
    for (int i = threadIdx.x; i < LW * ROWW; i += 256) tile[i] = 0.0f;
    __syncthreads();

    const int blk   = blockIdx.x;            // 0 .. BB*TILES-1
    const int tilei = blk % TILES;
    const int tx    = tilei % NTX;
    const int ty    = tilei / NTX;
    const int b     = blk / TILES;
    const int n0    = tx * TS;
    const int m0    = ty * TS;

    // 256 threads -> 32 rows x 8 col-groups of 4 consecutive pixels (float4 loads)
    const int lrow = threadIdx.x >> 3;        // 0..31
    const int lc4  = (threadIdx.x & 7) << 2;  // 0,4,...,28
    const int gm   = m0 + lrow;
    const int gn   = n0 + lc4;

    for (int t = 0; t < TT; ++t) {            // all 12 slices in one block
        const size_t base = ((size_t)((b * TT + t) * MM + gm)) * NN + gn;
        const float4 vr = *reinterpret_cast<const float4*>(xr + base);
        float4 vi = make_float4(0.f, 0.f, 0.f, 0.f);
        if (CPLX) vi = *reinterpret_cast<const float4*>(xi + base);
        const float4 ua = *reinterpret_cast<const float4*>(u + 2 * base);
        const float4 ub = *reinterpret_cast<const float4*>(u + 2 * base + 4);
        const float re[4]  = {vr.x, vr.y, vr.z, vr.w};
        const float im[4]  = {vi.x, vi.y, vi.z, vi.w};
        const float dxs[4] = {ua.x, ua.z, ub.x, ub.z};
        const float dys[4] = {ua.y, ua.w, ub.y, ub.w};
        #pragma unroll
        for (int j = 0; j < 4; ++j) {
            const float fx = (float)(gn + j) + dxs[j];
            const float fy = (float)gm + dys[j];
            const float x0f = floorf(fx);
            const float y0f = floorf(fy);
            const int   x0  = (int)x0f;
            const int   y0  = (int)y0f;
            const float frx = fx - x0f;
            const float fry = fy - y0f;
            const float wx[2] = {1.0f - frx, frx};
            const float wy[2] = {1.0f - fry, fry};
            #pragma unroll
            for (int cy = 0; cy < 2; ++cy) {
                const int yc = y0 + cy;
                if ((unsigned)yc >= (unsigned)MM) continue;
                #pragma unroll
                for (int cx = 0; cx < 2; ++cx) {
                    const int xc = x0 + cx;
                    if ((unsigned)xc >= (unsigned)NN) continue;
                    const float w  = wx[cx] * wy[cy];
                    const int  lr  = yc - (m0 - HALO);
                    const int  lc  = xc - (n0 - HALO);
                    if ((unsigned)lr < (unsigned)LW && (unsigned)lc < (unsigned)LW) {
                        if (CPLX) {
                            float* p = &tile[lr * ROWW + lc * 2];
                            atomicAdd(p,     w * re[j]);   // ds_add_f32
                            atomicAdd(p + 1, w * im[j]);
                        } else {
                            atomicAdd(&tile[lr * ROWW + lc], w * re[j]);
                        }
                    } else {
                        // out-of-halo (|u| > ~8 sigma): ~never, but must be correct.
                        // Lands in `out` BEFORE phase 2 reads it (stream order).
                        if (CPLX) {
                            float* q = out + (((size_t)b * MM + yc) * NN + xc) * 2;
                            unsafeAtomicAdd(q,     w * re[j]);
                            unsafeAtomicAdd(q + 1, w * im[j]);
                        } else {
                            unsafeAtomicAdd(out + ((size_t)b * MM + yc) * NN + xc,
                                            w * re[j]);
                        }
                    }
                }
            }
        }
    }
    __syncthreads();

    if (USE_WS) {
        // Plain coalesced store of the compact halo tile to ws.
        float* dst = ws + (size_t)blk * ELEMS;
        for (int i = threadIdx.x; i < ELEMS; i += 256) {
            if (CPLX) {
                const int pix  = i >> 1;
                const int comp = i & 1;
                dst[i] = tile[(pix / LW) * ROWW + (pix % LW) * 2 + comp];
            } else {
                dst[i] = tile[(i / LW) * ROWW + (i % LW)];
            }
        }
    } else {
        // Fallback (ws too small): atomic flush as before.
        for (int i = threadIdx.x; i < LW * LW; i += 256) {
            const int lr = i / LW;
            const int lc = i - lr * LW;
            const int gy = m0 - HALO + lr;
            const int gx = n0 - HALO + lc;
            if ((unsigned)gy < (unsigned)MM && (unsigned)gx < (unsigned)NN) {
                if (CPLX) {
                    const float vre = tile[lr * ROWW + lc * 2];
                    const float vim = tile[lr * ROWW + lc * 2 + 1];
                    if (vre != 0.0f || vim != 0.0f) {
                        float* q = out + (((size_t)b * MM + gy) * NN + gx) * 2;
                        unsafeAtomicAdd(q,     vre);
                        unsafeAtomicAdd(q + 1, vim);
                    }
                } else {
                    const float v = tile[lr * ROWW + lc];
                    if (v != 0.0f)
                        unsafeAtomicAdd(out + ((size_t)b * MM + gy) * NN + gx, v);
                }
            }
        }
    }
}

// ---------------- Phase 2: gather <=4 covering tiles per output pixel -------
template<bool CPLX>
__global__ __launch_bounds__(256)
void splat_phase2(const float* __restrict__ ws, float* __restrict__ out)
{
    constexpr int ELEMS = CPLX ? (LW * LW * 2) : (LW * LW);
    const int idx = blockIdx.x * 256 + threadIdx.x;      // 0 .. BB*MM*NN-1
    const int b   = idx / (MM * NN);
    const int rem = idx - b * (MM * NN);
    const int y   = rem / NN;
    const int x   = rem - y * NN;

    const int ty0 = y >> 5, ry = y & 31;
    const int tx0 = x >> 5, rx = x & 31;

    // per-axis covering tiles: own + (above if ry<HALO) + (below if ry>=TS-HALO)
    int tys[2]; int nty = 0;
    tys[nty++] = ty0;
    if (ry < HALO      && ty0 > 0)       tys[nty++] = ty0 - 1;
    if (ry >= TS-HALO  && ty0 < NTY-1)   tys[nty++] = ty0 + 1;
    int txs[2]; int ntx = 0;
    txs[ntx++] = tx0;
    if (rx < HALO      && tx0 > 0)       txs[ntx++] = tx0 - 1;
    if (rx >= TS-HALO  && tx0 < NTX-1)   txs[ntx++] = tx0 + 1;

    float sre = 0.0f, sim = 0.0f;
    for (int a = 0; a < nty; ++a) {
        const int ty = tys[a];
        const int lr = y - (ty * TS - HALO);             // 0..47
        for (int c = 0; c < ntx; ++c) {
            const int tx = txs[c];
            const int lc = x - (tx * TS - HALO);         // 0..47
            const float* src = ws + ((size_t)(b * TILES + ty * NTX + tx)) * ELEMS;
            if (CPLX) {
                sre += src[(lr * LW + lc) * 2];
                sim += src[(lr * LW + lc) * 2 + 1];
            } else {
                sre += src[lr * LW + lc];
            }
        }
    }
    if (CPLX) {
        out[2 * idx]     += sre;   // += keeps rare phase-1 OOB atomics + memset zero
        out[2 * idx + 1] += sim;
    } else {
        out[idx] += sre;
    }
}

extern "C" void kernel_launch(void* const* d_in, const int* in_sizes, int n_in,
                              void* d_out, int out_size, void* d_ws, size_t ws_size,
                              hipStream_t stream) {
    const float* xr = (const float*)d_in[0];
    const float* xi = (const float*)d_in[1];
    const float* u  = (const float*)d_in[2];
    float* out = (float*)d_out;
    float* ws  = (float*)d_ws;

    // Zero the output (harness poisons with 0xAA); phase 2 does +=.
    hipMemsetAsync(d_out, 0, (size_t)out_size * sizeof(float), stream);

    const bool cplx = (out_size >= 2 * BB * MM * NN);
    const int  grid1 = BB * TILES;                       // 1152
    const int  grid2 = (BB * MM * NN) / 256;             // 4608 (exact)
    const size_t need = (size_t)grid1 * LW * LW * (cplx ? 2 : 1) * sizeof(float);

    if (ws_size >= need) {
        if (cplx) {
            splat_phase1<true , true ><<<grid1, 256, 0, stream>>>(xr, xi, u, out, ws);
            splat_phase2<true ><<<grid2, 256, 0, stream>>>(ws, out);
        } else {
            splat_phase1<false, true ><<<grid1, 256, 0, stream>>>(xr, xi, u, out, ws);
            splat_phase2<false><<<grid2, 256, 0, stream>>>(ws, out);
        }
    } else {
        // ws too small: single-kernel atomic-flush fallback
        if (cplx)
            splat_phase1<true , false><<<grid1, 256, 0, stream>>>(xr, xi, u, out, ws);
        else
            splat_phase1<false, false><<<grid1, 256, 0, stream>>>(xr, xi, u, out, ws);
    }
}